// Round 10
// baseline (156.534 us; speedup 1.0000x reference)
//
#include <hip/hip_runtime.h>
#include <hip/hip_bf16.h>
#include <math.h>

#define BATCH   4096
#define DIM     1024
#define NGROUPS 1024
#define INV_T   10.0f
#define RANK_W  0.1f
#define SCORE_W 0.01f

#define BI 128       // q rows per block
#define BJ 256       // a rows per block
#define KC 32        // k per stage
#define NT (DIM/KC)  // 32 K-steps
#define NFRAG_Q (BI/16)          // 8
#define NFRAG   (BI/16 + BJ/16)  // 24 fragments per stage
#define NSTG    3                // fragments staged per wave (24 / 8 waves)
#define FRAG_ELEMS 512           // 16 rows x 32 k bf16

typedef float  floatx4 __attribute__((ext_vector_type(4)));
typedef __bf16 bf16x8  __attribute__((ext_vector_type(8)));
typedef __bf16 bf16x4  __attribute__((ext_vector_type(4)));

// async 16B/lane global->LDS: LDS dest is wave-uniform base + lane*16
#define ASYNC_COPY16(gptr, lptr)                                              \
    __builtin_amdgcn_global_load_lds(                                         \
        (const __attribute__((address_space(1))) void*)(gptr),                \
        (__attribute__((address_space(3))) void*)(lptr), 16, 0, 0)

// ---------------------------------------------------------------------------
// Kernel 1: prep.
// Block 0: the entire group-weight computation, LDS-resident (starts first,
// hides under the conversion blocks). Also zeroes out[0..1].
// Blocks [1,512]: fp32 -> bf16 conversion of Q and A, BATCHED: each thread
// issues all 16 independent dwordx4 loads before converting/storing (MLP=16),
// so the conversion is BW-bound, not latency-bound. 512 blocks = 2/CU in ONE
// scheduling round (44 KB static LDS caps this kernel at 3 blocks/CU).
// ---------------------------------------------------------------------------
__global__ __launch_bounds__(256) void prep_kernel(
    const float* __restrict__ Q, const float* __restrict__ A,
    __bf16* __restrict__ Qb, __bf16* __restrict__ Ab,
    const int* __restrict__ qid, const float* __restrict__ ranks,
    const float* __restrict__ scores, float* __restrict__ w,
    float* __restrict__ out)
{
    const int tid = threadIdx.x;

    if (blockIdx.x > 0) {
        const int base = (blockIdx.x - 1) * 256 + tid;   // 0..131071
        const int STR  = 512 * 256;                      // 131072 float4
        float4 q[8], a[8];
        #pragma unroll
        for (int k = 0; k < 8; ++k) q[k] = ((const float4*)Q)[base + k * STR];
        #pragma unroll
        for (int k = 0; k < 8; ++k) a[k] = ((const float4*)A)[base + k * STR];
        #pragma unroll
        for (int k = 0; k < 8; ++k) {
            bf16x4 b;
            b[0] = (__bf16)q[k].x; b[1] = (__bf16)q[k].y;
            b[2] = (__bf16)q[k].z; b[3] = (__bf16)q[k].w;
            ((bf16x4*)Qb)[base + k * STR] = b;
            b[0] = (__bf16)a[k].x; b[1] = (__bf16)a[k].y;
            b[2] = (__bf16)a[k].z; b[3] = (__bf16)a[k].w;
            ((bf16x4*)Ab)[base + k * STR] = b;
        }
        return;
    }

    // ---- single weight block (blockIdx 0): everything in LDS ----
    // scores >= 0, so float bit patterns are order-preserving as ints.
    if (tid < 2) out[tid] = 0.f;       // zero loss/acc accumulators

    __shared__ int   qidS[BATCH];      // 16 KB
    __shared__ float scoS[BATCH];      // 16 KB
    __shared__ int   gmaxS[NGROUPS];   // 4 KB (float bits)
    __shared__ int   gminS[NGROUPS];   // 4 KB (float bits)
    __shared__ float wsumS[NGROUPS];   // 4 KB

    #pragma unroll
    for (int k = 0; k < BATCH / 256; ++k) {
        const int j = tid + k * 256;
        qidS[j] = qid[j];
        scoS[j] = scores[j];
    }
    #pragma unroll
    for (int k = 0; k < NGROUPS / 256; ++k) {
        const int g = tid + k * 256;
        gmaxS[g] = 0;              // bits(0.0f) <= bits of any nonneg score
        gminS[g] = 0x7F800000;     // bits(+inf)
        wsumS[g] = 0.f;
    }
    __syncthreads();

    #pragma unroll
    for (int k = 0; k < BATCH / 256; ++k) {
        const int j = tid + k * 256;
        const int g = qidS[j];
        const int sb = __float_as_int(scoS[j]);
        atomicMax(&gmaxS[g], sb);
        atomicMin(&gminS[g], sb);
    }
    __syncthreads();

    float u[BATCH / 256];
    #pragma unroll
    for (int k = 0; k < BATCH / 256; ++k) {
        const int j = tid + k * 256;
        const int g = qidS[j];
        const float gmax = __int_as_float(gmaxS[g]);
        const float gmin = __int_as_float(gminS[g]);
        const float d    = gmax - gmin;
        const float invd = (d > 0.f) ? 1.f / d : 0.f;
        const float norm = (scoS[j] - gmin) * invd;
        u[k] = __expf(-RANK_W * ranks[j] + SCORE_W * norm);
        atomicAdd(&wsumS[g], u[k]);
    }
    __syncthreads();

    #pragma unroll
    for (int k = 0; k < BATCH / 256; ++k) {
        const int j = tid + k * 256;
        w[j] = u[k] / wsumS[qidS[j]];   // wsum > 0: group of j is nonempty
    }
}

// ---------------------------------------------------------------------------
// Kernel 2: fused sim = (Qb Ab^T)/T with online per-row (max, sumexp,
// weighted-sum, argmax) partials per 64-col slice.  (Verified R5/R7/R9 core.)
// 128x256 block tile, 8 waves of 64x64, fragment-major LDS (0 conflicts).
// ONE barrier per K-step, 3 LDS buffers, counted vmcnt(3).
// ---------------------------------------------------------------------------
__global__ __launch_bounds__(512, 4) void fused_simloss_kernel(
    const __bf16* __restrict__ Qb, const __bf16* __restrict__ Ab,
    const int* __restrict__ qid, const float* __restrict__ w,
    float* __restrict__ Pm, float* __restrict__ Pl, float* __restrict__ Ps,
    float* __restrict__ Pbv, int* __restrict__ Pbi)
{
    __shared__ __bf16 sbuf[3][NFRAG * FRAG_ELEMS];   // 3 x 24 KB = 72 KB

    const int jb = blockIdx.x, ib = blockIdx.y;
    const int i0 = ib * BI, j0 = jb * BJ;
    const int tid = threadIdx.x, wid = tid >> 6, lane = tid & 63;
    const int wm = wid >> 2, wn = wid & 3;      // 2x4 wave grid, 64x64 tiles
    const int quad = lane >> 4, l16 = lane & 15;

    floatx4 acc[4][4];
    #pragma unroll
    for (int m = 0; m < 4; ++m)
        #pragma unroll
        for (int n = 0; n < 4; ++n)
            #pragma unroll
            for (int c = 0; c < 4; ++c) acc[m][n][c] = 0.f;

    // staging: wave `wid` owns fragments f = wid*3 .. wid*3+2
    const int lr = lane & 15;
    const int lk = (lane >> 4) * 8;
    const __bf16* src[NSTG];
    #pragma unroll
    for (int c = 0; c < NSTG; ++c) {
        const int f = wid * NSTG + c;
        src[c] = (f < NFRAG_Q)
               ? Qb + (size_t)(i0 + f * 16 + lr) * DIM + lk
               : Ab + (size_t)(j0 + (f - NFRAG_Q) * 16 + lr) * DIM + lk;
    }

    #define STAGE(bufptr, k0)                                                 \
        do {                                                                  \
            _Pragma("unroll")                                                 \
            for (int c = 0; c < NSTG; ++c)                                    \
                ASYNC_COPY16(src[c] + (k0),                                   \
                             (__bf16*)(bufptr) + (wid * NSTG + c) * FRAG_ELEMS); \
        } while (0)

    // rotating buffer pointers (named vars, never runtime-indexed -> regs)
    __bf16* bprev = sbuf[2];   // free at t=0 (prologue stages only 0,1)
    __bf16* bcur  = sbuf[0];
    __bf16* bnext = sbuf[1];

    STAGE(bcur, 0);            // tile 0 -> buf0
    STAGE(bnext, KC);          // tile 1 -> buf1

    for (int t = 0; t < NT; ++t) {
        // single barrier per K-step; counted vmcnt: tile t landed,
        // tile t+1's 3 copies stay in flight.
        if (t < NT - 1) asm volatile("s_waitcnt vmcnt(3)\n\ts_barrier" ::: "memory");
        else            asm volatile("s_waitcnt vmcnt(0)\n\ts_barrier" ::: "memory");

        // STAGE first (T3 recipe): tile t+2 into the buffer read at t-1
        if (t + 2 < NT) STAGE(bprev, (t + 2) * KC);

        const __bf16* cur = bcur;
        bf16x8 qf[4], af[4];
        #pragma unroll
        for (int mf = 0; mf < 4; ++mf)
            qf[mf] = *(const bf16x8*)&cur[(wm * 4 + mf) * FRAG_ELEMS + lane * 8];
        #pragma unroll
        for (int nf = 0; nf < 4; ++nf)
            af[nf] = *(const bf16x8*)&cur[(NFRAG_Q + wn * 4 + nf) * FRAG_ELEMS + lane * 8];

        __builtin_amdgcn_s_setprio(1);
        #pragma unroll
        for (int nf = 0; nf < 4; ++nf)
            #pragma unroll
            for (int mf = 0; mf < 4; ++mf)
                acc[mf][nf] = __builtin_amdgcn_mfma_f32_16x16x32_bf16(
                    qf[mf], af[nf], acc[mf][nf], 0, 0, 0);
        __builtin_amdgcn_s_setprio(0);

        // rotate: {prev,cur,next} <- {cur,next,prev}
        __bf16* tmp = bprev;
        bprev = bcur; bcur = bnext; bnext = tmp;
    }
    #undef STAGE

    // ---- epilogue: (m, l, s, argmax) per row within this wave's 64-col slice
    int cq[4]; float cw[4];
    #pragma unroll
    for (int n = 0; n < 4; ++n) {
        int col = j0 + wn * 64 + n * 16 + l16;
        cq[n] = qid[col];
        cw[n] = w[col];
    }
    const int slice = jb * 4 + wn;             // 0..63

    #pragma unroll
    for (int m = 0; m < 4; ++m) {
        #pragma unroll
        for (int reg = 0; reg < 4; ++reg) {
            const int row = i0 + wm * 64 + m * 16 + quad * 4 + reg;
            const int rq  = qid[row];

            float v[4];
            #pragma unroll
            for (int n = 0; n < 4; ++n) v[n] = acc[m][n][reg] * INV_T;

            // pass 1: slice-wide max
            float pm = fmaxf(fmaxf(v[0], v[1]), fmaxf(v[2], v[3]));
            #pragma unroll
            for (int d = 1; d < 16; d <<= 1)
                pm = fmaxf(pm, __shfl_xor(pm, d, 64));

            // pass 2: local sums against the global max + local argmax
            float ll = __expf(v[0] - pm) + __expf(v[1] - pm) +
                       __expf(v[2] - pm) + __expf(v[3] - pm);
            float ls = 0.f;
            #pragma unroll
            for (int n = 0; n < 4; ++n) ls += (cq[n] == rq) ? cw[n] * v[n] : 0.f;

            float bv = v[0];
            int   bi = j0 + wn * 64 + l16;
            #pragma unroll
            for (int n = 1; n < 4; ++n) {
                int c = j0 + wn * 64 + n * 16 + l16;
                if (v[n] > bv) { bv = v[n]; bi = c; }
            }

            // combined sum + argmax reduce over 16 lanes
            #pragma unroll
            for (int d = 1; d < 16; d <<= 1) {
                ll += __shfl_xor(ll, d, 64);
                ls += __shfl_xor(ls, d, 64);
                float obv = __shfl_xor(bv, d, 64);
                int   obi = __shfl_xor(bi, d, 64);
                if (obv > bv || (obv == bv && obi < bi)) { bv = obv; bi = obi; }
            }
            if (l16 == 0) {
                int idx = row * 64 + slice;
                Pm[idx] = pm; Pl[idx] = ll; Ps[idx] = ls;
                Pbv[idx] = bv; Pbi[idx] = bi;
            }
        }
    }
}

// ---------------------------------------------------------------------------
// Kernel 3: merge 64 slice-partials per row -> loss/acc accumulated into
// out[0..1]. 64 blocks x 1024 threads: each block reduces 64 rows
// (16 waves x 4 rows), combines in LDS, then a SINGLE pair of atomicAdds
// per block (128 same-line atomics total).
// ---------------------------------------------------------------------------
__global__ __launch_bounds__(1024) void row_reduce_kernel(
    const float* __restrict__ Pm, const float* __restrict__ Pl,
    const float* __restrict__ Ps, const float* __restrict__ Pbv,
    const int* __restrict__ Pbi, const int* __restrict__ qid,
    float* __restrict__ out)
{
    const int wv   = threadIdx.x >> 6;   // 0..15
    const int lane = threadIdx.x & 63;

    float s1 = 0.f, s2 = 0.f;
    #pragma unroll
    for (int k = 0; k < 4; ++k) {
        const int r   = blockIdx.x * 64 + wv * 4 + k;
        const int idx = r * 64 + lane;

        float m = Pm[idx], l = Pl[idx], s = Ps[idx], bv = Pbv[idx];
        int   bi = Pbi[idx];

        #pragma unroll
        for (int d = 1; d < 64; d <<= 1) {
            float om  = __shfl_xor(m, d, 64);
            float ol  = __shfl_xor(l, d, 64);
            float os  = __shfl_xor(s, d, 64);
            float obv = __shfl_xor(bv, d, 64);
            int   obi = __shfl_xor(bi, d, 64);
            float nm = fmaxf(m, om);
            l = l * __expf(m - nm) + ol * __expf(om - nm);
            m = nm;
            s += os;
            if (obv > bv || (obv == bv && obi < bi)) { bv = obv; bi = obi; }
        }
        if (lane == 0) {
            s1 += (m + logf(l)) - s;
            s2 += (qid[bi] == qid[r]) ? 1.f : 0.f;
        }
    }

    __shared__ float r1[16], r2[16];
    if (lane == 0) { r1[wv] = s1; r2[wv] = s2; }
    __syncthreads();
    if (threadIdx.x == 0) {
        float t1 = 0.f, t2 = 0.f;
        #pragma unroll
        for (int i = 0; i < 16; ++i) { t1 += r1[i]; t2 += r2[i]; }
        atomicAdd(&out[0], t1 * (1.f / (float)BATCH));
        atomicAdd(&out[1], t2 * (1.f / (float)BATCH));
    }
}

// ---------------------------------------------------------------------------
extern "C" void kernel_launch(void* const* d_in, const int* in_sizes, int n_in,
                              void* d_out, int out_size, void* d_ws, size_t ws_size,
                              hipStream_t stream)
{
    const float* Q      = (const float*)d_in[0];
    const float* A      = (const float*)d_in[1];
    const int*   qid    = (const int*)d_in[2];
    const float* ranks  = (const float*)d_in[3];
    const float* scores = (const float*)d_in[4];
    float* out = (float*)d_out;

    // ws layout: Qb[4M bf16]=8MB | Ab[4M bf16]=8MB | w[4096] |
    //            Pm,Pl,Ps,Pbv[262144] | Pbi[262144]
    __bf16* Qb = (__bf16*)d_ws;
    __bf16* Ab = Qb + (size_t)BATCH * DIM;
    float* w   = (float*)(Ab + (size_t)BATCH * DIM);
    float* Pm  = w + BATCH;
    float* Pl  = Pm + BATCH * 64;
    float* Ps  = Pl + BATCH * 64;
    float* Pbv = Ps + BATCH * 64;
    int*   Pbi = (int*)(Pbv + BATCH * 64);

    prep_kernel<<<513, 256, 0, stream>>>(Q, A, Qb, Ab, qid, ranks, scores, w, out);

    dim3 grid(BATCH / BJ, BATCH / BI);  // 16 x 32 = 512 blocks
    fused_simloss_kernel<<<grid, 512, 0, stream>>>(Qb, Ab, qid, w, Pm, Pl, Ps, Pbv, Pbi);

    row_reduce_kernel<<<64, 1024, 0, stream>>>(Pm, Pl, Ps, Pbv, Pbi, qid, out);
}

// Round 12
// 156.494 us; speedup vs baseline: 1.0003x; 1.0003x over previous
//
#include <hip/hip_runtime.h>
#include <hip/hip_bf16.h>
#include <math.h>

#define BATCH   4096
#define DIM     1024
#define NGROUPS 1024
#define INV_T   10.0f
#define RANK_W  0.1f
#define SCORE_W 0.01f

#define BI 128       // q rows per block
#define BJ 256       // a rows per block
#define KC 32        // k per stage
#define NT (DIM/KC)  // 32 K-steps
#define NFRAG_Q (BI/16)          // 8
#define NFRAG   (BI/16 + BJ/16)  // 24 fragments per stage
#define NSTG    3                // fragments staged per wave (24 / 8 waves)
#define FRAG_ELEMS 512           // 16 rows x 32 k bf16

typedef float  floatx4 __attribute__((ext_vector_type(4)));
typedef __bf16 bf16x8  __attribute__((ext_vector_type(8)));
typedef __bf16 bf16x4  __attribute__((ext_vector_type(4)));

// async 16B/lane global->LDS: LDS dest is wave-uniform base + lane*16
#define ASYNC_COPY16(gptr, lptr)                                              \
    __builtin_amdgcn_global_load_lds(                                         \
        (const __attribute__((address_space(1))) void*)(gptr),                \
        (__attribute__((address_space(3))) void*)(lptr), 16, 0, 0)

// ---------------------------------------------------------------------------
// Kernel 1: prep.
// Block 0: the entire group-weight computation, LDS-resident. Also zeroes
// out[0..1]. Blocks [1,512]: fp32 -> bf16 conversion of Q and A, MLP=16.
// ---------------------------------------------------------------------------
__global__ __launch_bounds__(256) void prep_kernel(
    const float* __restrict__ Q, const float* __restrict__ A,
    __bf16* __restrict__ Qb, __bf16* __restrict__ Ab,
    const int* __restrict__ qid, const float* __restrict__ ranks,
    const float* __restrict__ scores, float* __restrict__ w,
    float* __restrict__ out)
{
    const int tid = threadIdx.x;

    if (blockIdx.x > 0) {
        const int base = (blockIdx.x - 1) * 256 + tid;   // 0..131071
        const int STR  = 512 * 256;                      // 131072 float4
        float4 q[8], a[8];
        #pragma unroll
        for (int k = 0; k < 8; ++k) q[k] = ((const float4*)Q)[base + k * STR];
        #pragma unroll
        for (int k = 0; k < 8; ++k) a[k] = ((const float4*)A)[base + k * STR];
        #pragma unroll
        for (int k = 0; k < 8; ++k) {
            bf16x4 b;
            b[0] = (__bf16)q[k].x; b[1] = (__bf16)q[k].y;
            b[2] = (__bf16)q[k].z; b[3] = (__bf16)q[k].w;
            ((bf16x4*)Qb)[base + k * STR] = b;
            b[0] = (__bf16)a[k].x; b[1] = (__bf16)a[k].y;
            b[2] = (__bf16)a[k].z; b[3] = (__bf16)a[k].w;
            ((bf16x4*)Ab)[base + k * STR] = b;
        }
        return;
    }

    // ---- single weight block (blockIdx 0): everything in LDS ----
    // scores >= 0, so float bit patterns are order-preserving as ints.
    if (tid < 2) out[tid] = 0.f;       // zero loss/acc accumulators

    __shared__ int   qidS[BATCH];      // 16 KB
    __shared__ float scoS[BATCH];      // 16 KB
    __shared__ int   gmaxS[NGROUPS];   // 4 KB (float bits)
    __shared__ int   gminS[NGROUPS];   // 4 KB (float bits)
    __shared__ float wsumS[NGROUPS];   // 4 KB

    #pragma unroll
    for (int k = 0; k < BATCH / 256; ++k) {
        const int j = tid + k * 256;
        qidS[j] = qid[j];
        scoS[j] = scores[j];
    }
    #pragma unroll
    for (int k = 0; k < NGROUPS / 256; ++k) {
        const int g = tid + k * 256;
        gmaxS[g] = 0;              // bits(0.0f) <= bits of any nonneg score
        gminS[g] = 0x7F800000;     // bits(+inf)
        wsumS[g] = 0.f;
    }
    __syncthreads();

    #pragma unroll
    for (int k = 0; k < BATCH / 256; ++k) {
        const int j = tid + k * 256;
        const int g = qidS[j];
        const int sb = __float_as_int(scoS[j]);
        atomicMax(&gmaxS[g], sb);
        atomicMin(&gminS[g], sb);
    }
    __syncthreads();

    float u[BATCH / 256];
    #pragma unroll
    for (int k = 0; k < BATCH / 256; ++k) {
        const int j = tid + k * 256;
        const int g = qidS[j];
        const float gmax = __int_as_float(gmaxS[g]);
        const float gmin = __int_as_float(gminS[g]);
        const float d    = gmax - gmin;
        const float invd = (d > 0.f) ? 1.f / d : 0.f;
        const float norm = (scoS[j] - gmin) * invd;
        u[k] = __expf(-RANK_W * ranks[j] + SCORE_W * norm);
        atomicAdd(&wsumS[g], u[k]);
    }
    __syncthreads();

    #pragma unroll
    for (int k = 0; k < BATCH / 256; ++k) {
        const int j = tid + k * 256;
        w[j] = u[k] / wsumS[qidS[j]];   // wsum > 0: group of j is nonempty
    }
}

// ---------------------------------------------------------------------------
// Kernel 2: fused sim = (Qb Ab^T)/T with online per-row (max, sumexp,
// weighted-sum, argmax) partials per 64-col slice.
// 128x256 block tile, 8 waves of 64x64, fragment-major LDS (0 conflicts),
// 3 LDS buffers, counted vmcnt(3).
// R11: K-step split into TWO barrier-separated sub-phases
// (T3 template shape: {reads + stage-issue -> MFMA cluster} x2) so resident
// waves stagger roles instead of bursting the LDS pipe in lockstep:
//   P0: vmcnt(3)+barrier; read qf0-3,af0-1; stage 2/3; setprio MFMA(nf0,1)
//   P1: barrier;          read af2-3;       stage 1/3; setprio MFMA(nf2,3)
// ---------------------------------------------------------------------------
__global__ __launch_bounds__(512, 4) void fused_simloss_kernel(
    const __bf16* __restrict__ Qb, const __bf16* __restrict__ Ab,
    const int* __restrict__ qid, const float* __restrict__ w,
    float* __restrict__ Pm, float* __restrict__ Pl, float* __restrict__ Ps,
    float* __restrict__ Pbv, int* __restrict__ Pbi)
{
    __shared__ __bf16 sbuf[3][NFRAG * FRAG_ELEMS];   // 3 x 24 KB = 72 KB

    const int jb = blockIdx.x, ib = blockIdx.y;
    const int i0 = ib * BI, j0 = jb * BJ;
    const int tid = threadIdx.x, wid = tid >> 6, lane = tid & 63;
    const int wm = wid >> 2, wn = wid & 3;      // 2x4 wave grid, 64x64 tiles
    const int quad = lane >> 4, l16 = lane & 15;

    floatx4 acc[4][4];
    #pragma unroll
    for (int m = 0; m < 4; ++m)
        #pragma unroll
        for (int n = 0; n < 4; ++n)
            #pragma unroll
            for (int c = 0; c < 4; ++c) acc[m][n][c] = 0.f;

    // staging: wave `wid` owns fragments f = wid*3 .. wid*3+2
    const int lr = lane & 15;
    const int lk = (lane >> 4) * 8;
    const __bf16* src[NSTG];
    #pragma unroll
    for (int c = 0; c < NSTG; ++c) {
        const int f = wid * NSTG + c;
        src[c] = (f < NFRAG_Q)
               ? Qb + (size_t)(i0 + f * 16 + lr) * DIM + lk
               : Ab + (size_t)(j0 + (f - NFRAG_Q) * 16 + lr) * DIM + lk;
    }

    #define STAGE(bufptr, k0)                                                 \
        do {                                                                  \
            _Pragma("unroll")                                                 \
            for (int c = 0; c < NSTG; ++c)                                    \
                ASYNC_COPY16(src[c] + (k0),                                   \
                             (__bf16*)(bufptr) + (wid * NSTG + c) * FRAG_ELEMS); \
        } while (0)

    // rotating buffer pointers (named vars, never runtime-indexed -> regs)
    __bf16* bprev = sbuf[2];   // free at t=0 (prologue stages only 0,1)
    __bf16* bcur  = sbuf[0];
    __bf16* bnext = sbuf[1];

    STAGE(bcur, 0);            // tile 0 -> buf0
    STAGE(bnext, KC);          // tile 1 -> buf1

    for (int t = 0; t < NT; ++t) {
        // ---- P0 entry: own tile-t copies landed + all waves synced
        if (t < NT - 1) asm volatile("s_waitcnt vmcnt(3)\n\ts_barrier" ::: "memory");
        else            asm volatile("s_waitcnt vmcnt(0)\n\ts_barrier" ::: "memory");

        const __bf16* cur = bcur;
        const int kf = (t + 2) * KC;
        bf16x8 qf[4], af[4];

        // P0 reads: qf0-3, af0-1
        #pragma unroll
        for (int mf = 0; mf < 4; ++mf)
            qf[mf] = *(const bf16x8*)&cur[(wm * 4 + mf) * FRAG_ELEMS + lane * 8];
        af[0] = *(const bf16x8*)&cur[(NFRAG_Q + wn * 4 + 0) * FRAG_ELEMS + lane * 8];
        af[1] = *(const bf16x8*)&cur[(NFRAG_Q + wn * 4 + 1) * FRAG_ELEMS + lane * 8];
        // P0 stage: 2 of 3 copies of tile t+2 into bprev
        if (t + 2 < NT) {
            ASYNC_COPY16(src[0] + kf, bprev + (wid * NSTG + 0) * FRAG_ELEMS);
            ASYNC_COPY16(src[1] + kf, bprev + (wid * NSTG + 1) * FRAG_ELEMS);
        }
        __builtin_amdgcn_s_setprio(1);
        #pragma unroll
        for (int nf = 0; nf < 2; ++nf)
            #pragma unroll
            for (int mf = 0; mf < 4; ++mf)
                acc[mf][nf] = __builtin_amdgcn_mfma_f32_16x16x32_bf16(
                    qf[mf], af[nf], acc[mf][nf], 0, 0, 0);
        __builtin_amdgcn_s_setprio(0);
        __builtin_amdgcn_sched_barrier(0);   // pin P0 work before mid barrier

        // ---- P1
        __builtin_amdgcn_s_barrier();
        af[2] = *(const bf16x8*)&cur[(NFRAG_Q + wn * 4 + 2) * FRAG_ELEMS + lane * 8];
        af[3] = *(const bf16x8*)&cur[(NFRAG_Q + wn * 4 + 3) * FRAG_ELEMS + lane * 8];
        if (t + 2 < NT)
            ASYNC_COPY16(src[2] + kf, bprev + (wid * NSTG + 2) * FRAG_ELEMS);
        __builtin_amdgcn_s_setprio(1);
        #pragma unroll
        for (int nf = 2; nf < 4; ++nf)
            #pragma unroll
            for (int mf = 0; mf < 4; ++mf)
                acc[mf][nf] = __builtin_amdgcn_mfma_f32_16x16x32_bf16(
                    qf[mf], af[nf], acc[mf][nf], 0, 0, 0);
        __builtin_amdgcn_s_setprio(0);
        __builtin_amdgcn_sched_barrier(0);   // pin P1 work before next barrier

        // rotate: {prev,cur,next} <- {cur,next,prev}
        __bf16* tmp = bprev;
        bprev = bcur; bcur = bnext; bnext = tmp;
    }
    #undef STAGE

    // ---- epilogue: (m, l, s, argmax) per row within this wave's 64-col slice
    int cq[4]; float cw[4];
    #pragma unroll
    for (int n = 0; n < 4; ++n) {
        int col = j0 + wn * 64 + n * 16 + l16;
        cq[n] = qid[col];
        cw[n] = w[col];
    }
    const int slice = jb * 4 + wn;             // 0..63

    #pragma unroll
    for (int m = 0; m < 4; ++m) {
        #pragma unroll
        for (int reg = 0; reg < 4; ++reg) {
            const int row = i0 + wm * 64 + m * 16 + quad * 4 + reg;
            const int rq  = qid[row];

            float v[4];
            #pragma unroll
            for (int n = 0; n < 4; ++n) v[n] = acc[m][n][reg] * INV_T;

            // pass 1: slice-wide max
            float pm = fmaxf(fmaxf(v[0], v[1]), fmaxf(v[2], v[3]));
            #pragma unroll
            for (int d = 1; d < 16; d <<= 1)
                pm = fmaxf(pm, __shfl_xor(pm, d, 64));

            // pass 2: local sums against the global max + local argmax
            float ll = __expf(v[0] - pm) + __expf(v[1] - pm) +
                       __expf(v[2] - pm) + __expf(v[3] - pm);
            float ls = 0.f;
            #pragma unroll
            for (int n = 0; n < 4; ++n) ls += (cq[n] == rq) ? cw[n] * v[n] : 0.f;

            float bv = v[0];
            int   bi = j0 + wn * 64 + l16;
            #pragma unroll
            for (int n = 1; n < 4; ++n) {
                int c = j0 + wn * 64 + n * 16 + l16;
                if (v[n] > bv) { bv = v[n]; bi = c; }
            }

            // combined sum + argmax reduce over 16 lanes
            #pragma unroll
            for (int d = 1; d < 16; d <<= 1) {
                ll += __shfl_xor(ll, d, 64);
                ls += __shfl_xor(ls, d, 64);
                float obv = __shfl_xor(bv, d, 64);
                int   obi = __shfl_xor(bi, d, 64);
                if (obv > bv || (obv == bv && obi < bi)) { bv = obv; bi = obi; }
            }
            if (l16 == 0) {
                int idx = row * 64 + slice;
                Pm[idx] = pm; Pl[idx] = ll; Ps[idx] = ls;
                Pbv[idx] = bv; Pbi[idx] = bi;
            }
        }
    }
}

// ---------------------------------------------------------------------------
// Kernel 3: merge 64 slice-partials per row -> loss/acc accumulated into
// out[0..1]. 64 blocks x 1024 threads, one atomicAdd pair per block.
// ---------------------------------------------------------------------------
__global__ __launch_bounds__(1024) void row_reduce_kernel(
    const float* __restrict__ Pm, const float* __restrict__ Pl,
    const float* __restrict__ Ps, const float* __restrict__ Pbv,
    const int* __restrict__ Pbi, const int* __restrict__ qid,
    float* __restrict__ out)
{
    const int wv   = threadIdx.x >> 6;   // 0..15
    const int lane = threadIdx.x & 63;

    float s1 = 0.f, s2 = 0.f;
    #pragma unroll
    for (int k = 0; k < 4; ++k) {
        const int r   = blockIdx.x * 64 + wv * 4 + k;
        const int idx = r * 64 + lane;

        float m = Pm[idx], l = Pl[idx], s = Ps[idx], bv = Pbv[idx];
        int   bi = Pbi[idx];

        #pragma unroll
        for (int d = 1; d < 64; d <<= 1) {
            float om  = __shfl_xor(m, d, 64);
            float ol  = __shfl_xor(l, d, 64);
            float os  = __shfl_xor(s, d, 64);
            float obv = __shfl_xor(bv, d, 64);
            int   obi = __shfl_xor(bi, d, 64);
            float nm = fmaxf(m, om);
            l = l * __expf(m - nm) + ol * __expf(om - nm);
            m = nm;
            s += os;
            if (obv > bv || (obv == bv && obi < bi)) { bv = obv; bi = obi; }
        }
        if (lane == 0) {
            s1 += (m + logf(l)) - s;
            s2 += (qid[bi] == qid[r]) ? 1.f : 0.f;
        }
    }

    __shared__ float r1[16], r2[16];
    if (lane == 0) { r1[wv] = s1; r2[wv] = s2; }
    __syncthreads();
    if (threadIdx.x == 0) {
        float t1 = 0.f, t2 = 0.f;
        #pragma unroll
        for (int i = 0; i < 16; ++i) { t1 += r1[i]; t2 += r2[i]; }
        atomicAdd(&out[0], t1 * (1.f / (float)BATCH));
        atomicAdd(&out[1], t2 * (1.f / (float)BATCH));
    }
}

// ---------------------------------------------------------------------------
extern "C" void kernel_launch(void* const* d_in, const int* in_sizes, int n_in,
                              void* d_out, int out_size, void* d_ws, size_t ws_size,
                              hipStream_t stream)
{
    const float* Q      = (const float*)d_in[0];
    const float* A      = (const float*)d_in[1];
    const int*   qid    = (const int*)d_in[2];
    const float* ranks  = (const float*)d_in[3];
    const float* scores = (const float*)d_in[4];
    float* out = (float*)d_out;

    // ws layout: Qb[4M bf16]=8MB | Ab[4M bf16]=8MB | w[4096] |
    //            Pm,Pl,Ps,Pbv[262144] | Pbi[262144]
    __bf16* Qb = (__bf16*)d_ws;
    __bf16* Ab = Qb + (size_t)BATCH * DIM;
    float* w   = (float*)(Ab + (size_t)BATCH * DIM);
    float* Pm  = w + BATCH;
    float* Pl  = Pm + BATCH * 64;
    float* Ps  = Pl + BATCH * 64;
    float* Pbv = Ps + BATCH * 64;
    int*   Pbi = (int*)(Pbv + BATCH * 64);

    prep_kernel<<<513, 256, 0, stream>>>(Q, A, Qb, Ab, qid, ranks, scores, w, out);

    dim3 grid(BATCH / BJ, BATCH / BI);  // 16 x 32 = 512 blocks
    fused_simloss_kernel<<<grid, 512, 0, stream>>>(Qb, Ab, qid, w, Pm, Pl, Ps, Pbv, Pbi);

    row_reduce_kernel<<<64, 1024, 0, stream>>>(Pm, Pl, Ps, Pbv, Pbi, qid, out);
}

// Round 18
// 153.532 us; speedup vs baseline: 1.0196x; 1.0193x over previous
//
#include <hip/hip_runtime.h>
#include <hip/hip_bf16.h>
#include <math.h>

#define BATCH   4096
#define DIM     1024
#define NGROUPS 1024
#define INV_T   10.0f
#define RANK_W  0.1f
#define SCORE_W 0.01f

#define BI 128       // q rows per block
#define BJ 256       // a rows per block
#define KC 32        // k per stage
#define NT (DIM/KC)  // 32 K-steps
#define NFRAG_Q (BI/16)          // 8
#define NFRAG   (BI/16 + BJ/16)  // 24 fragments per stage
#define NSTG    3                // fragments staged per wave (24 / 8 waves)
#define FRAG_ELEMS 512           // 16 rows x 32 k bf16

typedef float  floatx4 __attribute__((ext_vector_type(4)));
typedef __bf16 bf16x8  __attribute__((ext_vector_type(8)));
typedef __bf16 bf16x4  __attribute__((ext_vector_type(4)));

// async 16B/lane global->LDS: LDS dest is wave-uniform base + lane*16
#define ASYNC_COPY16(gptr, lptr)                                              \
    __builtin_amdgcn_global_load_lds(                                         \
        (const __attribute__((address_space(1))) void*)(gptr),                \
        (__attribute__((address_space(3))) void*)(lptr), 16, 0, 0)

// ---- DPP 16-lane XOR-butterfly (VALU pipe; replaces ds_bpermute shuffles) --
// stage controls: xor1=quad_perm(1,0,3,2), xor2=quad_perm(2,3,0,1),
// xor7=row_half_mirror, xor15=row_mirror. All stay within a DPP row (16
// lanes) == our l16 reduce group. 4 stages give every lane the full
// 16-lane reduction (merge bits: b0, b1, b0-2, b0-3).
#define DPP_XOR1  0xB1
#define DPP_XOR2  0x4E
#define DPP_XOR7  0x141
#define DPP_XOR15 0x140

template<int C> __device__ __forceinline__ float dppf(float x) {
    return __builtin_bit_cast(float,
        __builtin_amdgcn_update_dpp(0, __builtin_bit_cast(int, x),
                                    C, 0xF, 0xF, true));
}
template<int C> __device__ __forceinline__ int dppi(int x) {
    return __builtin_amdgcn_update_dpp(0, x, C, 0xF, 0xF, true);
}

// ---------------------------------------------------------------------------
// Kernel 1: prep.
// Block 0: the entire group-weight computation, LDS-resident. Also zeroes
// out[0..1]. Blocks [1,512]: fp32 -> bf16 conversion of Q and A, MLP=16.
// ---------------------------------------------------------------------------
__global__ __launch_bounds__(256) void prep_kernel(
    const float* __restrict__ Q, const float* __restrict__ A,
    __bf16* __restrict__ Qb, __bf16* __restrict__ Ab,
    const int* __restrict__ qid, const float* __restrict__ ranks,
    const float* __restrict__ scores, float* __restrict__ w,
    float* __restrict__ out)
{
    const int tid = threadIdx.x;

    if (blockIdx.x > 0) {
        const int base = (blockIdx.x - 1) * 256 + tid;   // 0..131071
        const int STR  = 512 * 256;                      // 131072 float4
        float4 q[8], a[8];
        #pragma unroll
        for (int k = 0; k < 8; ++k) q[k] = ((const float4*)Q)[base + k * STR];
        #pragma unroll
        for (int k = 0; k < 8; ++k) a[k] = ((const float4*)A)[base + k * STR];
        #pragma unroll
        for (int k = 0; k < 8; ++k) {
            bf16x4 b;
            b[0] = (__bf16)q[k].x; b[1] = (__bf16)q[k].y;
            b[2] = (__bf16)q[k].z; b[3] = (__bf16)q[k].w;
            ((bf16x4*)Qb)[base + k * STR] = b;
            b[0] = (__bf16)a[k].x; b[1] = (__bf16)a[k].y;
            b[2] = (__bf16)a[k].z; b[3] = (__bf16)a[k].w;
            ((bf16x4*)Ab)[base + k * STR] = b;
        }
        return;
    }

    // ---- single weight block (blockIdx 0): everything in LDS ----
    // scores >= 0, so float bit patterns are order-preserving as ints.
    if (tid < 2) out[tid] = 0.f;       // zero loss/acc accumulators

    __shared__ int   qidS[BATCH];      // 16 KB
    __shared__ float scoS[BATCH];      // 16 KB
    __shared__ int   gmaxS[NGROUPS];   // 4 KB (float bits)
    __shared__ int   gminS[NGROUPS];   // 4 KB (float bits)
    __shared__ float wsumS[NGROUPS];   // 4 KB

    #pragma unroll
    for (int k = 0; k < BATCH / 256; ++k) {
        const int j = tid + k * 256;
        qidS[j] = qid[j];
        scoS[j] = scores[j];
    }
    #pragma unroll
    for (int k = 0; k < NGROUPS / 256; ++k) {
        const int g = tid + k * 256;
        gmaxS[g] = 0;              // bits(0.0f) <= bits of any nonneg score
        gminS[g] = 0x7F800000;     // bits(+inf)
        wsumS[g] = 0.f;
    }
    __syncthreads();

    #pragma unroll
    for (int k = 0; k < BATCH / 256; ++k) {
        const int j = tid + k * 256;
        const int g = qidS[j];
        const int sb = __float_as_int(scoS[j]);
        atomicMax(&gmaxS[g], sb);
        atomicMin(&gminS[g], sb);
    }
    __syncthreads();

    float u[BATCH / 256];
    #pragma unroll
    for (int k = 0; k < BATCH / 256; ++k) {
        const int j = tid + k * 256;
        const int g = qidS[j];
        const float gmax = __int_as_float(gmaxS[g]);
        const float gmin = __int_as_float(gminS[g]);
        const float d    = gmax - gmin;
        const float invd = (d > 0.f) ? 1.f / d : 0.f;
        const float norm = (scoS[j] - gmin) * invd;
        u[k] = __expf(-RANK_W * ranks[j] + SCORE_W * norm);
        atomicAdd(&wsumS[g], u[k]);
    }
    __syncthreads();

    #pragma unroll
    for (int k = 0; k < BATCH / 256; ++k) {
        const int j = tid + k * 256;
        w[j] = u[k] / wsumS[qidS[j]];   // wsum > 0: group of j is nonempty
    }
}

// ---------------------------------------------------------------------------
// Kernel 2: fused sim = (Qb Ab^T)/T with online per-row (max, sumexp,
// weighted-sum, argmax) partials per 64-col slice.
// K-loop: verified R5/R10 core — 128x256 tile, 8 waves of 64x64,
// fragment-major LDS (0 conflicts), 3 buffers, 1 barrier/K-step,
// counted vmcnt(3).
// R13: epilogue reduces moved from ds_bpermute (__shfl_xor) to DPP
// XOR-butterflies on the VALU pipe — removes 320 DS-ops/wave (the
// post-K-loop DS burst: ~5120 DS ops/CU ~= 13 us on the shared LDS pipe).
// ---------------------------------------------------------------------------
__global__ __launch_bounds__(512, 4) void fused_simloss_kernel(
    const __bf16* __restrict__ Qb, const __bf16* __restrict__ Ab,
    const int* __restrict__ qid, const float* __restrict__ w,
    float* __restrict__ Pm, float* __restrict__ Pl, float* __restrict__ Ps,
    float* __restrict__ Pbv, int* __restrict__ Pbi)
{
    __shared__ __bf16 sbuf[3][NFRAG * FRAG_ELEMS];   // 3 x 24 KB = 72 KB

    const int jb = blockIdx.x, ib = blockIdx.y;
    const int i0 = ib * BI, j0 = jb * BJ;
    const int tid = threadIdx.x, wid = tid >> 6, lane = tid & 63;
    const int wm = wid >> 2, wn = wid & 3;      // 2x4 wave grid, 64x64 tiles
    const int quad = lane >> 4, l16 = lane & 15;

    floatx4 acc[4][4];
    #pragma unroll
    for (int m = 0; m < 4; ++m)
        #pragma unroll
        for (int n = 0; n < 4; ++n)
            #pragma unroll
            for (int c = 0; c < 4; ++c) acc[m][n][c] = 0.f;

    // staging: wave `wid` owns fragments f = wid*3 .. wid*3+2
    const int lr = lane & 15;
    const int lk = (lane >> 4) * 8;
    const __bf16* src[NSTG];
    #pragma unroll
    for (int c = 0; c < NSTG; ++c) {
        const int f = wid * NSTG + c;
        src[c] = (f < NFRAG_Q)
               ? Qb + (size_t)(i0 + f * 16 + lr) * DIM + lk
               : Ab + (size_t)(j0 + (f - NFRAG_Q) * 16 + lr) * DIM + lk;
    }

    #define STAGE(bufptr, k0)                                                 \
        do {                                                                  \
            _Pragma("unroll")                                                 \
            for (int c = 0; c < NSTG; ++c)                                    \
                ASYNC_COPY16(src[c] + (k0),                                   \
                             (__bf16*)(bufptr) + (wid * NSTG + c) * FRAG_ELEMS); \
        } while (0)

    // rotating buffer pointers (named vars, never runtime-indexed -> regs)
    __bf16* bprev = sbuf[2];   // free at t=0 (prologue stages only 0,1)
    __bf16* bcur  = sbuf[0];
    __bf16* bnext = sbuf[1];

    STAGE(bcur, 0);            // tile 0 -> buf0
    STAGE(bnext, KC);          // tile 1 -> buf1

    for (int t = 0; t < NT; ++t) {
        // single barrier per K-step; counted vmcnt: tile t landed,
        // tile t+1's 3 copies stay in flight.
        if (t < NT - 1) asm volatile("s_waitcnt vmcnt(3)\n\ts_barrier" ::: "memory");
        else            asm volatile("s_waitcnt vmcnt(0)\n\ts_barrier" ::: "memory");

        // STAGE first (T3 recipe): tile t+2 into the buffer read at t-1
        if (t + 2 < NT) STAGE(bprev, (t + 2) * KC);

        const __bf16* cur = bcur;
        bf16x8 qf[4], af[4];
        #pragma unroll
        for (int mf = 0; mf < 4; ++mf)
            qf[mf] = *(const bf16x8*)&cur[(wm * 4 + mf) * FRAG_ELEMS + lane * 8];
        #pragma unroll
        for (int nf = 0; nf < 4; ++nf)
            af[nf] = *(const bf16x8*)&cur[(NFRAG_Q + wn * 4 + nf) * FRAG_ELEMS + lane * 8];

        __builtin_amdgcn_s_setprio(1);
        #pragma unroll
        for (int nf = 0; nf < 4; ++nf)
            #pragma unroll
            for (int mf = 0; mf < 4; ++mf)
                acc[mf][nf] = __builtin_amdgcn_mfma_f32_16x16x32_bf16(
                    qf[mf], af[nf], acc[mf][nf], 0, 0, 0);
        __builtin_amdgcn_s_setprio(0);

        // rotate: {prev,cur,next} <- {cur,next,prev}
        __bf16* tmp = bprev;
        bprev = bcur; bcur = bnext; bnext = tmp;
    }
    #undef STAGE

    // ---- epilogue: (m, l, s, argmax) per row within this wave's 64-col slice
    int cq[4]; float cw[4];
    #pragma unroll
    for (int n = 0; n < 4; ++n) {
        int col = j0 + wn * 64 + n * 16 + l16;
        cq[n] = qid[col];
        cw[n] = w[col];
    }
    const int slice = jb * 4 + wn;             // 0..63

    #pragma unroll
    for (int m = 0; m < 4; ++m) {
        #pragma unroll
        for (int reg = 0; reg < 4; ++reg) {
            const int row = i0 + wm * 64 + m * 16 + quad * 4 + reg;
            const int rq  = qid[row];

            float v[4];
            #pragma unroll
            for (int n = 0; n < 4; ++n) v[n] = acc[m][n][reg] * INV_T;

            // pass 1: slice-wide max via DPP butterfly (VALU, no LDS)
            float pm = fmaxf(fmaxf(v[0], v[1]), fmaxf(v[2], v[3]));
            pm = fmaxf(pm, dppf<DPP_XOR1>(pm));
            pm = fmaxf(pm, dppf<DPP_XOR2>(pm));
            pm = fmaxf(pm, dppf<DPP_XOR7>(pm));
            pm = fmaxf(pm, dppf<DPP_XOR15>(pm));

            // pass 2: local sums against the global max + local argmax
            float ll = __expf(v[0] - pm) + __expf(v[1] - pm) +
                       __expf(v[2] - pm) + __expf(v[3] - pm);
            float ls = 0.f;
            #pragma unroll
            for (int n = 0; n < 4; ++n) ls += (cq[n] == rq) ? cw[n] * v[n] : 0.f;

            float bv = v[0];
            int   bi = j0 + wn * 64 + l16;
            #pragma unroll
            for (int n = 1; n < 4; ++n) {
                int c = j0 + wn * 64 + n * 16 + l16;
                if (v[n] > bv) { bv = v[n]; bi = c; }
            }

            // combined sum + argmax 16-lane reduce via DPP butterfly
            #define RSTAGE(C)                                                  \
                {                                                              \
                    ll += dppf<C>(ll);                                         \
                    ls += dppf<C>(ls);                                         \
                    float obv = dppf<C>(bv);                                   \
                    int   obi = dppi<C>(bi);                                   \
                    if (obv > bv || (obv == bv && obi < bi)) { bv = obv; bi = obi; } \
                }
            RSTAGE(DPP_XOR1)
            RSTAGE(DPP_XOR2)
            RSTAGE(DPP_XOR7)
            RSTAGE(DPP_XOR15)
            #undef RSTAGE

            if (l16 == 0) {
                int idx = row * 64 + slice;
                Pm[idx] = pm; Pl[idx] = ll; Ps[idx] = ls;
                Pbv[idx] = bv; Pbi[idx] = bi;
            }
        }
    }
}

// ---------------------------------------------------------------------------
// Kernel 3: merge 64 slice-partials per row -> loss/acc accumulated into
// out[0..1]. 64 blocks x 1024 threads, one atomicAdd pair per block.
// ---------------------------------------------------------------------------
__global__ __launch_bounds__(1024) void row_reduce_kernel(
    const float* __restrict__ Pm, const float* __restrict__ Pl,
    const float* __restrict__ Ps, const float* __restrict__ Pbv,
    const int* __restrict__ Pbi, const int* __restrict__ qid,
    float* __restrict__ out)
{
    const int wv   = threadIdx.x >> 6;   // 0..15
    const int lane = threadIdx.x & 63;

    float s1 = 0.f, s2 = 0.f;
    #pragma unroll
    for (int k = 0; k < 4; ++k) {
        const int r   = blockIdx.x * 64 + wv * 4 + k;
        const int idx = r * 64 + lane;

        float m = Pm[idx], l = Pl[idx], s = Ps[idx], bv = Pbv[idx];
        int   bi = Pbi[idx];

        #pragma unroll
        for (int d = 1; d < 64; d <<= 1) {
            float om  = __shfl_xor(m, d, 64);
            float ol  = __shfl_xor(l, d, 64);
            float os  = __shfl_xor(s, d, 64);
            float obv = __shfl_xor(bv, d, 64);
            int   obi = __shfl_xor(bi, d, 64);
            float nm = fmaxf(m, om);
            l = l * __expf(m - nm) + ol * __expf(om - nm);
            m = nm;
            s += os;
            if (obv > bv || (obv == bv && obi < bi)) { bv = obv; bi = obi; }
        }
        if (lane == 0) {
            s1 += (m + logf(l)) - s;
            s2 += (qid[bi] == qid[r]) ? 1.f : 0.f;
        }
    }

    __shared__ float r1[16], r2[16];
    if (lane == 0) { r1[wv] = s1; r2[wv] = s2; }
    __syncthreads();
    if (threadIdx.x == 0) {
        float t1 = 0.f, t2 = 0.f;
        #pragma unroll
        for (int i = 0; i < 16; ++i) { t1 += r1[i]; t2 += r2[i]; }
        atomicAdd(&out[0], t1 * (1.f / (float)BATCH));
        atomicAdd(&out[1], t2 * (1.f / (float)BATCH));
    }
}

// ---------------------------------------------------------------------------
extern "C" void kernel_launch(void* const* d_in, const int* in_sizes, int n_in,
                              void* d_out, int out_size, void* d_ws, size_t ws_size,
                              hipStream_t stream)
{
    const float* Q      = (const float*)d_in[0];
    const float* A      = (const float*)d_in[1];
    const int*   qid    = (const int*)d_in[2];
    const float* ranks  = (const float*)d_in[3];
    const float* scores = (const float*)d_in[4];
    float* out = (float*)d_out;

    // ws layout: Qb[4M bf16]=8MB | Ab[4M bf16]=8MB | w[4096] |
    //            Pm,Pl,Ps,Pbv[262144] | Pbi[262144]
    __bf16* Qb = (__bf16*)d_ws;
    __bf16* Ab = Qb + (size_t)BATCH * DIM;
    float* w   = (float*)(Ab + (size_t)BATCH * DIM);
    float* Pm  = w + BATCH;
    float* Pl  = Pm + BATCH * 64;
    float* Ps  = Pl + BATCH * 64;
    float* Pbv = Ps + BATCH * 64;
    int*   Pbi = (int*)(Pbv + BATCH * 64);

    prep_kernel<<<513, 256, 0, stream>>>(Q, A, Qb, Ab, qid, ranks, scores, w, out);

    dim3 grid(BATCH / BJ, BATCH / BI);  // 16 x 32 = 512 blocks
    fused_simloss_kernel<<<grid, 512, 0, stream>>>(Qb, Ab, qid, w, Pm, Pl, Ps, Pbv, Pbi);

    row_reduce_kernel<<<64, 1024, 0, stream>>>(Pm, Pl, Ps, Pbv, Pbi, qid, out);
}

// Round 20
// 146.948 us; speedup vs baseline: 1.0652x; 1.0448x over previous
//
#include <hip/hip_runtime.h>
#include <hip/hip_bf16.h>
#include <math.h>

#define BATCH   4096
#define DIM     1024
#define NGROUPS 1024
#define INV_T   10.0f
#define RANK_W  0.1f
#define SCORE_W 0.01f

#define BI 256       // q rows per block
#define BJ 256       // a rows per block
#define KC 32        // k per stage
#define NT (DIM/KC)  // 32 K-steps
#define NFRAG_Q (BI/16)          // 16
#define NFRAG   (BI/16 + BJ/16)  // 32 fragments per stage
#define NSTG    4                // fragments staged per wave (32 / 8 waves)
#define FRAG_ELEMS 512           // 16 rows x 32 k bf16

typedef float  floatx4 __attribute__((ext_vector_type(4)));
typedef __bf16 bf16x8  __attribute__((ext_vector_type(8)));
typedef __bf16 bf16x4  __attribute__((ext_vector_type(4)));

// async 16B/lane global->LDS: LDS dest is wave-uniform base + lane*16
#define ASYNC_COPY16(gptr, lptr)                                              \
    __builtin_amdgcn_global_load_lds(                                         \
        (const __attribute__((address_space(1))) void*)(gptr),                \
        (__attribute__((address_space(3))) void*)(lptr), 16, 0, 0)

// ---- DPP 16-lane XOR-butterfly (VALU pipe; replaces ds_bpermute shuffles) --
#define DPP_XOR1  0xB1
#define DPP_XOR2  0x4E
#define DPP_XOR7  0x141
#define DPP_XOR15 0x140

template<int C> __device__ __forceinline__ float dppf(float x) {
    return __builtin_bit_cast(float,
        __builtin_amdgcn_update_dpp(0, __builtin_bit_cast(int, x),
                                    C, 0xF, 0xF, true));
}
template<int C> __device__ __forceinline__ int dppi(int x) {
    return __builtin_amdgcn_update_dpp(0, x, C, 0xF, 0xF, true);
}

// ---------------------------------------------------------------------------
// Kernel 1: prep.  (verified R9/R10 version, unchanged)
// Block 0: group-weight computation, LDS-resident; zeroes out[0..1].
// Blocks [1,512]: fp32 -> bf16 conversion, MLP=16.
// ---------------------------------------------------------------------------
__global__ __launch_bounds__(256) void prep_kernel(
    const float* __restrict__ Q, const float* __restrict__ A,
    __bf16* __restrict__ Qb, __bf16* __restrict__ Ab,
    const int* __restrict__ qid, const float* __restrict__ ranks,
    const float* __restrict__ scores, float* __restrict__ w,
    float* __restrict__ out)
{
    const int tid = threadIdx.x;

    if (blockIdx.x > 0) {
        const int base = (blockIdx.x - 1) * 256 + tid;   // 0..131071
        const int STR  = 512 * 256;                      // 131072 float4
        float4 q[8], a[8];
        #pragma unroll
        for (int k = 0; k < 8; ++k) q[k] = ((const float4*)Q)[base + k * STR];
        #pragma unroll
        for (int k = 0; k < 8; ++k) a[k] = ((const float4*)A)[base + k * STR];
        #pragma unroll
        for (int k = 0; k < 8; ++k) {
            bf16x4 b;
            b[0] = (__bf16)q[k].x; b[1] = (__bf16)q[k].y;
            b[2] = (__bf16)q[k].z; b[3] = (__bf16)q[k].w;
            ((bf16x4*)Qb)[base + k * STR] = b;
            b[0] = (__bf16)a[k].x; b[1] = (__bf16)a[k].y;
            b[2] = (__bf16)a[k].z; b[3] = (__bf16)a[k].w;
            ((bf16x4*)Ab)[base + k * STR] = b;
        }
        return;
    }

    // ---- single weight block (blockIdx 0): everything in LDS ----
    if (tid < 2) out[tid] = 0.f;       // zero loss/acc accumulators

    __shared__ int   qidS[BATCH];      // 16 KB
    __shared__ float scoS[BATCH];      // 16 KB
    __shared__ int   gmaxS[NGROUPS];   // 4 KB (float bits)
    __shared__ int   gminS[NGROUPS];   // 4 KB (float bits)
    __shared__ float wsumS[NGROUPS];   // 4 KB

    #pragma unroll
    for (int k = 0; k < BATCH / 256; ++k) {
        const int j = tid + k * 256;
        qidS[j] = qid[j];
        scoS[j] = scores[j];
    }
    #pragma unroll
    for (int k = 0; k < NGROUPS / 256; ++k) {
        const int g = tid + k * 256;
        gmaxS[g] = 0;              // bits(0.0f) <= bits of any nonneg score
        gminS[g] = 0x7F800000;     // bits(+inf)
        wsumS[g] = 0.f;
    }
    __syncthreads();

    #pragma unroll
    for (int k = 0; k < BATCH / 256; ++k) {
        const int j = tid + k * 256;
        const int g = qidS[j];
        const int sb = __float_as_int(scoS[j]);
        atomicMax(&gmaxS[g], sb);
        atomicMin(&gminS[g], sb);
    }
    __syncthreads();

    float u[BATCH / 256];
    #pragma unroll
    for (int k = 0; k < BATCH / 256; ++k) {
        const int j = tid + k * 256;
        const int g = qidS[j];
        const float gmax = __int_as_float(gmaxS[g]);
        const float gmin = __int_as_float(gminS[g]);
        const float d    = gmax - gmin;
        const float invd = (d > 0.f) ? 1.f / d : 0.f;
        const float norm = (scoS[j] - gmin) * invd;
        u[k] = __expf(-RANK_W * ranks[j] + SCORE_W * norm);
        atomicAdd(&wsumS[g], u[k]);
    }
    __syncthreads();

    #pragma unroll
    for (int k = 0; k < BATCH / 256; ++k) {
        const int j = tid + k * 256;
        w[j] = u[k] / wsumS[qidS[j]];   // wsum > 0: group of j is nonempty
    }
}

// ---------------------------------------------------------------------------
// Kernel 2: fused sim = (Qb Ab^T)/T with online per-row (max, sumexp,
// weighted-sum, argmax) partials per 64-col slice.
// R19: 256x256 block tile, 8 waves of 64x128 (acc[4][8]) — LDS-read cost
// drops from 0.5 to 0.375 b128/MFMA (the dominant pipe per R18 accounting).
// Sync skeleton identical to verified R5/R18: 3 rotating buffers,
// 1 barrier/K-step, counted vmcnt(NSTG), setprio MFMA, DPP epilogue.
// 96 KB LDS -> 1 block/CU; grid 16x16.
// ---------------------------------------------------------------------------
__global__ __launch_bounds__(512, 2) void fused_simloss_kernel(
    const __bf16* __restrict__ Qb, const __bf16* __restrict__ Ab,
    const int* __restrict__ qid, const float* __restrict__ w,
    float* __restrict__ Pm, float* __restrict__ Pl, float* __restrict__ Ps,
    float* __restrict__ Pbv, int* __restrict__ Pbi)
{
    __shared__ __bf16 sbuf[3][NFRAG * FRAG_ELEMS];   // 3 x 32 KB = 96 KB

    const int jb = blockIdx.x, ib = blockIdx.y;
    const int i0 = ib * BI, j0 = jb * BJ;
    const int tid = threadIdx.x, wid = tid >> 6, lane = tid & 63;
    const int wm = wid >> 1, wn = wid & 1;      // 4x2 wave grid, 64x128 tiles
    const int quad = lane >> 4, l16 = lane & 15;

    floatx4 acc[4][8];
    #pragma unroll
    for (int m = 0; m < 4; ++m)
        #pragma unroll
        for (int n = 0; n < 8; ++n)
            #pragma unroll
            for (int c = 0; c < 4; ++c) acc[m][n][c] = 0.f;

    // staging: wave `wid` owns fragments f = wid*4 .. wid*4+3
    const int lr = lane & 15;
    const int lk = (lane >> 4) * 8;
    const __bf16* src[NSTG];
    #pragma unroll
    for (int c = 0; c < NSTG; ++c) {
        const int f = wid * NSTG + c;
        src[c] = (f < NFRAG_Q)
               ? Qb + (size_t)(i0 + f * 16 + lr) * DIM + lk
               : Ab + (size_t)(j0 + (f - NFRAG_Q) * 16 + lr) * DIM + lk;
    }

    #define STAGE(bufptr, k0)                                                 \
        do {                                                                  \
            _Pragma("unroll")                                                 \
            for (int c = 0; c < NSTG; ++c)                                    \
                ASYNC_COPY16(src[c] + (k0),                                   \
                             (__bf16*)(bufptr) + (wid * NSTG + c) * FRAG_ELEMS); \
        } while (0)

    // rotating buffer pointers (named vars, never runtime-indexed -> regs)
    __bf16* bprev = sbuf[2];   // free at t=0 (prologue stages only 0,1)
    __bf16* bcur  = sbuf[0];
    __bf16* bnext = sbuf[1];

    STAGE(bcur, 0);            // tile 0 -> buf0
    STAGE(bnext, KC);          // tile 1 -> buf1

    for (int t = 0; t < NT; ++t) {
        // single barrier per K-step; counted vmcnt: tile t landed,
        // tile t+1's 4 copies stay in flight.
        if (t < NT - 1) asm volatile("s_waitcnt vmcnt(4)\n\ts_barrier" ::: "memory");
        else            asm volatile("s_waitcnt vmcnt(0)\n\ts_barrier" ::: "memory");

        // STAGE first (T3 recipe): tile t+2 into the buffer read at t-1
        if (t + 2 < NT) STAGE(bprev, (t + 2) * KC);

        const __bf16* cur = bcur;
        bf16x8 qf[4], af[8];
        #pragma unroll
        for (int mf = 0; mf < 4; ++mf)
            qf[mf] = *(const bf16x8*)&cur[(wm * 4 + mf) * FRAG_ELEMS + lane * 8];
        #pragma unroll
        for (int nf = 0; nf < 8; ++nf)
            af[nf] = *(const bf16x8*)&cur[(NFRAG_Q + wn * 8 + nf) * FRAG_ELEMS + lane * 8];

        __builtin_amdgcn_s_setprio(1);
        #pragma unroll
        for (int nf = 0; nf < 8; ++nf)
            #pragma unroll
            for (int mf = 0; mf < 4; ++mf)
                acc[mf][nf] = __builtin_amdgcn_mfma_f32_16x16x32_bf16(
                    qf[mf], af[nf], acc[mf][nf], 0, 0, 0);
        __builtin_amdgcn_s_setprio(0);

        // rotate: {prev,cur,next} <- {cur,next,prev}
        __bf16* tmp = bprev;
        bprev = bcur; bcur = bnext; bnext = tmp;
    }
    #undef STAGE

    // ---- epilogue: (m, l, s, argmax) per row; this wave owns 64 rows x
    // 128 cols = TWO 64-col slices. DPP 16-lane butterflies (VALU pipe).
    int cq[8]; float cw[8];
    #pragma unroll
    for (int n = 0; n < 8; ++n) {
        int col = j0 + wn * 128 + n * 16 + l16;
        cq[n] = qid[col];
        cw[n] = w[col];
    }

    #pragma unroll
    for (int half = 0; half < 2; ++half) {
        const int nb = half * 4;                       // n-frag base
        const int slice = jb * 4 + wn * 2 + half;      // 0..63
        #pragma unroll
        for (int m = 0; m < 4; ++m) {
            #pragma unroll
            for (int reg = 0; reg < 4; ++reg) {
                const int row = i0 + wm * 64 + m * 16 + quad * 4 + reg;
                const int rq  = qid[row];

                float v[4];
                #pragma unroll
                for (int n = 0; n < 4; ++n) v[n] = acc[m][nb + n][reg] * INV_T;

                // pass 1: slice-wide max via DPP butterfly
                float pm = fmaxf(fmaxf(v[0], v[1]), fmaxf(v[2], v[3]));
                pm = fmaxf(pm, dppf<DPP_XOR1>(pm));
                pm = fmaxf(pm, dppf<DPP_XOR2>(pm));
                pm = fmaxf(pm, dppf<DPP_XOR7>(pm));
                pm = fmaxf(pm, dppf<DPP_XOR15>(pm));

                // pass 2: local sums against the global max + local argmax
                float ll = __expf(v[0] - pm) + __expf(v[1] - pm) +
                           __expf(v[2] - pm) + __expf(v[3] - pm);
                float ls = 0.f;
                #pragma unroll
                for (int n = 0; n < 4; ++n)
                    ls += (cq[nb + n] == rq) ? cw[nb + n] * v[n] : 0.f;

                float bv = v[0];
                int   bi = j0 + wn * 128 + nb * 16 + l16;
                #pragma unroll
                for (int n = 1; n < 4; ++n) {
                    int c = j0 + wn * 128 + (nb + n) * 16 + l16;
                    if (v[n] > bv) { bv = v[n]; bi = c; }
                }

                // combined sum + argmax 16-lane reduce via DPP butterfly
                #define RSTAGE(C)                                              \
                    {                                                          \
                        ll += dppf<C>(ll);                                     \
                        ls += dppf<C>(ls);                                     \
                        float obv = dppf<C>(bv);                               \
                        int   obi = dppi<C>(bi);                               \
                        if (obv > bv || (obv == bv && obi < bi)) { bv = obv; bi = obi; } \
                    }
                RSTAGE(DPP_XOR1)
                RSTAGE(DPP_XOR2)
                RSTAGE(DPP_XOR7)
                RSTAGE(DPP_XOR15)
                #undef RSTAGE

                if (l16 == 0) {
                    int idx = row * 64 + slice;
                    Pm[idx] = pm; Pl[idx] = ll; Ps[idx] = ls;
                    Pbv[idx] = bv; Pbi[idx] = bi;
                }
            }
        }
    }
}

// ---------------------------------------------------------------------------
// Kernel 3: merge 64 slice-partials per row -> loss/acc accumulated into
// out[0..1]. 64 blocks x 1024 threads, one atomicAdd pair per block.
// ---------------------------------------------------------------------------
__global__ __launch_bounds__(1024) void row_reduce_kernel(
    const float* __restrict__ Pm, const float* __restrict__ Pl,
    const float* __restrict__ Ps, const float* __restrict__ Pbv,
    const int* __restrict__ Pbi, const int* __restrict__ qid,
    float* __restrict__ out)
{
    const int wv   = threadIdx.x >> 6;   // 0..15
    const int lane = threadIdx.x & 63;

    float s1 = 0.f, s2 = 0.f;
    #pragma unroll
    for (int k = 0; k < 4; ++k) {
        const int r   = blockIdx.x * 64 + wv * 4 + k;
        const int idx = r * 64 + lane;

        float m = Pm[idx], l = Pl[idx], s = Ps[idx], bv = Pbv[idx];
        int   bi = Pbi[idx];

        #pragma unroll
        for (int d = 1; d < 64; d <<= 1) {
            float om  = __shfl_xor(m, d, 64);
            float ol  = __shfl_xor(l, d, 64);
            float os  = __shfl_xor(s, d, 64);
            float obv = __shfl_xor(bv, d, 64);
            int   obi = __shfl_xor(bi, d, 64);
            float nm = fmaxf(m, om);
            l = l * __expf(m - nm) + ol * __expf(om - nm);
            m = nm;
            s += os;
            if (obv > bv || (obv == bv && obi < bi)) { bv = obv; bi = obi; }
        }
        if (lane == 0) {
            s1 += (m + logf(l)) - s;
            s2 += (qid[bi] == qid[r]) ? 1.f : 0.f;
        }
    }

    __shared__ float r1[16], r2[16];
    if (lane == 0) { r1[wv] = s1; r2[wv] = s2; }
    __syncthreads();
    if (threadIdx.x == 0) {
        float t1 = 0.f, t2 = 0.f;
        #pragma unroll
        for (int i = 0; i < 16; ++i) { t1 += r1[i]; t2 += r2[i]; }
        atomicAdd(&out[0], t1 * (1.f / (float)BATCH));
        atomicAdd(&out[1], t2 * (1.f / (float)BATCH));
    }
}

// ---------------------------------------------------------------------------
extern "C" void kernel_launch(void* const* d_in, const int* in_sizes, int n_in,
                              void* d_out, int out_size, void* d_ws, size_t ws_size,
                              hipStream_t stream)
{
    const float* Q      = (const float*)d_in[0];
    const float* A      = (const float*)d_in[1];
    const int*   qid    = (const int*)d_in[2];
    const float* ranks  = (const float*)d_in[3];
    const float* scores = (const float*)d_in[4];
    float* out = (float*)d_out;

    // ws layout: Qb[4M bf16]=8MB | Ab[4M bf16]=8MB | w[4096] |
    //            Pm,Pl,Ps,Pbv[262144] | Pbi[262144]
    __bf16* Qb = (__bf16*)d_ws;
    __bf16* Ab = Qb + (size_t)BATCH * DIM;
    float* w   = (float*)(Ab + (size_t)BATCH * DIM);
    float* Pm  = w + BATCH;
    float* Pl  = Pm + BATCH * 64;
    float* Ps  = Pl + BATCH * 64;
    float* Pbv = Ps + BATCH * 64;
    int*   Pbi = (int*)(Pbv + BATCH * 64);

    prep_kernel<<<513, 256, 0, stream>>>(Q, A, Qb, Ab, qid, ranks, scores, w, out);

    dim3 grid(BATCH / BJ, BATCH / BI);  // 16 x 16 = 256 blocks
    fused_simloss_kernel<<<grid, 512, 0, stream>>>(Qb, Ab, qid, w, Pm, Pl, Ps, Pbv, Pbi);

    row_reduce_kernel<<<64, 1024, 0, stream>>>(Pm, Pl, Ps, Pbv, Pbi, qid, out);
}